// Round 1
// baseline (5337.777 us; speedup 1.0000x reference)
//
#include <hip/hip_runtime.h>
#include <hip/hip_bf16.h>

#define HID   100
#define SEQ   480
#define INP   640
#define NCLS  307200
#define G4    400   // 4*HID

// ---------------------------------------------------------------------------
// proj: xp[t][r] = (bih[r]+bhh[r]) + sum_{k<K} xin[t][k] * W[r][k]
// One block per timestep t; input row staged in LDS; 400 active threads.
// K = 640 (layer 0) or 100 (layers 1-3).
// ---------------------------------------------------------------------------
__global__ __launch_bounds__(512) void proj_kernel(
    const float* __restrict__ xin, const float* __restrict__ W,
    const float* __restrict__ bih, const float* __restrict__ bhh,
    float* __restrict__ xp, int K)
{
    __shared__ __align__(16) float xrow[INP];
    const int t = blockIdx.x;
    const int tid = threadIdx.x;
    const int K4 = K >> 2;

    for (int i = tid; i < K4; i += 512) {
        reinterpret_cast<float4*>(xrow)[i] =
            reinterpret_cast<const float4*>(xin + (size_t)t * K)[i];
    }
    __syncthreads();

    if (tid < G4) {
        const float4* wr = reinterpret_cast<const float4*>(W + (size_t)tid * K);
        float acc = bih[tid] + bhh[tid];
        #pragma unroll 5
        for (int k = 0; k < K4; ++k) {
            float4 w4 = wr[k];
            float4 x4 = reinterpret_cast<const float4*>(xrow)[k];
            acc = fmaf(w4.x, x4.x, acc);
            acc = fmaf(w4.y, x4.y, acc);
            acc = fmaf(w4.z, x4.z, acc);
            acc = fmaf(w4.w, x4.w, acc);
        }
        xp[(size_t)t * G4 + tid] = acc;
    }
}

// ---------------------------------------------------------------------------
// lstm_seq: sequential recurrence for one layer. ONE block, 512 threads
// (400 active). Thread r holds row r of Whh (100 f32) in registers.
// Per step: acc = xp[t][r] + Whh[r]·h  (h broadcast from LDS),
// gate exchange via LDS, threads 0..99 update (c,h), write h to LDS+global.
// xp is prefetched one timestep ahead to hide global-load latency.
// ---------------------------------------------------------------------------
__global__ __launch_bounds__(512) void lstm_seq(
    const float* __restrict__ xp,    // [SEQ][G4]
    const float* __restrict__ Whh,   // [G4][HID]
    float* __restrict__ hseq)        // [SEQ][HID]
{
    __shared__ __align__(16) float h_lds[HID + 4];
    __shared__ float gate_lds[G4];
    const int tid = threadIdx.x;

    float4 w[25];
    if (tid < G4) {
        const float4* wr = reinterpret_cast<const float4*>(Whh + (size_t)tid * HID);
        #pragma unroll
        for (int k = 0; k < 25; ++k) w[k] = wr[k];
    }
    if (tid < HID) h_lds[tid] = 0.f;
    float c = 0.f;
    float xp_next = (tid < G4) ? xp[tid] : 0.f;
    __syncthreads();

    for (int t = 0; t < SEQ; ++t) {
        float acc = xp_next;
        if (tid < G4 && t + 1 < SEQ) xp_next = xp[(size_t)(t + 1) * G4 + tid];

        if (tid < G4) {
            #pragma unroll
            for (int k = 0; k < 25; ++k) {
                float4 h4 = reinterpret_cast<const float4*>(h_lds)[k];
                acc = fmaf(w[k].x, h4.x, acc);
                acc = fmaf(w[k].y, h4.y, acc);
                acc = fmaf(w[k].z, h4.z, acc);
                acc = fmaf(w[k].w, h4.w, acc);
            }
            gate_lds[tid] = acc;
        }
        __syncthreads();

        if (tid < HID) {
            float gi = gate_lds[tid];
            float gf = gate_lds[HID + tid];
            float gg = gate_lds[2 * HID + tid];
            float go = gate_lds[3 * HID + tid];
            float si = 1.f / (1.f + __expf(-gi));
            float sf = 1.f / (1.f + __expf(-gf));
            float so = 1.f / (1.f + __expf(-go));
            float tg = tanhf(gg);
            c = sf * c + si * tg;
            float h = so * tanhf(c);
            h_lds[tid] = h;
            hseq[(size_t)t * HID + tid] = h;
        }
        __syncthreads();
    }
}

// ---------------------------------------------------------------------------
// fc_blend: out[c] = dot(hlast, fcW[c]) + fcb[c], optionally (.+blend)*0.5
// Thread per output row; h staged in LDS; float4 row loads.
// ---------------------------------------------------------------------------
__global__ __launch_bounds__(256) void fc_blend(
    const float* __restrict__ hlast,   // [HID]
    const float* __restrict__ fcW,     // [NCLS][HID]
    const float* __restrict__ fcb,     // [NCLS]
    const float* __restrict__ blend,   // [NCLS] or nullptr
    float* __restrict__ outp, int do_blend)
{
    __shared__ __align__(16) float h_lds[HID];
    const int tid = threadIdx.x;
    if (tid < 25) {
        reinterpret_cast<float4*>(h_lds)[tid] =
            reinterpret_cast<const float4*>(hlast)[tid];
    }
    __syncthreads();

    const int cidx = blockIdx.x * 256 + tid;
    const float4* wr = reinterpret_cast<const float4*>(fcW + (size_t)cidx * HID);
    float acc = fcb[cidx];
    #pragma unroll
    for (int k = 0; k < 25; ++k) {
        float4 w4 = wr[k];
        float4 h4 = reinterpret_cast<const float4*>(h_lds)[k];
        acc = fmaf(w4.x, h4.x, acc);
        acc = fmaf(w4.y, h4.y, acc);
        acc = fmaf(w4.z, h4.z, acc);
        acc = fmaf(w4.w, h4.w, acc);
    }
    if (do_blend) acc = (acc + blend[cidx]) * 0.5f;
    outp[cidx] = acc;
}

// ---------------------------------------------------------------------------
extern "C" void kernel_launch(void* const* d_in, const int* in_sizes, int n_in,
                              void* d_out, int out_size, void* d_ws, size_t ws_size,
                              hipStream_t stream)
{
    const float* x    = (const float*)d_in[0];
    const float* xn   = (const float*)d_in[1];
    const float* xnn  = (const float*)d_in[2];
    const float* Wih0 = (const float*)d_in[3];  // (3, 400, 640)
    const float* WihR = (const float*)d_in[4];  // (3, 3, 400, 100)
    const float* Whh  = (const float*)d_in[5];  // (3, 4, 400, 100)
    const float* bih  = (const float*)d_in[6];  // (3, 4, 400)
    const float* bhh  = (const float*)d_in[7];  // (3, 4, 400)
    const float* fcW  = (const float*)d_in[8];  // (3, 307200, 100)
    const float* fcb  = (const float*)d_in[9];  // (3, 307200)
    float* outp = (float*)d_out;
    float* ws = (float*)d_ws;

    float* xp  = ws;            // 192000 f32
    float* hA  = ws + 192000;   //  48000 f32
    float* hB  = ws + 240000;   //  48000 f32
    float* cur = ws + 288000;   // 307200 f32  (inter-stage activations)

    for (int s = 0; s < 3; ++s) {
        const float* stage_in = (s == 0) ? x : cur;

        // layer 0 (K=640 input)
        proj_kernel<<<SEQ, 512, 0, stream>>>(
            stage_in, Wih0 + (size_t)s * G4 * INP,
            bih + (size_t)(s * 4 + 0) * G4, bhh + (size_t)(s * 4 + 0) * G4,
            xp, INP);
        lstm_seq<<<1, 512, 0, stream>>>(
            xp, Whh + (size_t)(s * 4 + 0) * G4 * HID, hA);

        float* hin = hA;
        float* hout = hB;
        for (int l = 1; l < 4; ++l) {
            proj_kernel<<<SEQ, 512, 0, stream>>>(
                hin, WihR + (size_t)(s * 3 + (l - 1)) * G4 * HID,
                bih + (size_t)(s * 4 + l) * G4, bhh + (size_t)(s * 4 + l) * G4,
                xp, HID);
            lstm_seq<<<1, 512, 0, stream>>>(
                xp, Whh + (size_t)(s * 4 + l) * G4 * HID, hout);
            float* tmp = hin; hin = hout; hout = tmp;
        }
        // hin now points at layer-3 hidden sequence

        const float* blend = (s == 0) ? xn : (s == 1) ? xnn : nullptr;
        float* dst = (s == 2) ? outp : cur;
        fc_blend<<<NCLS / 256, 256, 0, stream>>>(
            hin + (size_t)(SEQ - 1) * HID,
            fcW + (size_t)s * NCLS * HID, fcb + (size_t)s * NCLS,
            blend, dst, (s < 2) ? 1 : 0);
    }
}

// Round 2
// 4001.360 us; speedup vs baseline: 1.3340x; 1.3340x over previous
//
#include <hip/hip_runtime.h>
#include <hip/hip_bf16.h>

#define HID   100
#define SEQ   480
#define INP   640
#define NCLS  307200
#define G4    400   // 4*HID

typedef float v2 __attribute__((ext_vector_type(2)));

__device__ __forceinline__ v2 fma2(v2 a, v2 b, v2 c) {
    return __builtin_elementwise_fma(a, b, c);
}
__device__ __forceinline__ float fast_sigmoid(float x) {
    return __builtin_amdgcn_rcpf(1.f + __expf(-x));
}
__device__ __forceinline__ float fast_tanh(float x) {
    return 1.f - 2.f * __builtin_amdgcn_rcpf(__expf(2.f * x) + 1.f);
}
__device__ __forceinline__ float rdlane(float v, int l) {
    return __uint_as_float(__builtin_amdgcn_readlane(__float_as_uint(v), l));
}

// ---------------------------------------------------------------------------
// proj: for row r (= gate*100+unit): acc = (bih[r]+bhh[r]) + xin[t]·W[r]
// Written TRANSPOSED to unit-major: xpT[t][unit][gate]  (so the lstm owner
// thread reads its 4 gate pre-activations as one float4).
// ---------------------------------------------------------------------------
__global__ __launch_bounds__(512) void proj_kernel(
    const float* __restrict__ xin, const float* __restrict__ W,
    const float* __restrict__ bih, const float* __restrict__ bhh,
    float* __restrict__ xpT, int K)
{
    __shared__ __align__(16) float xrow[INP];
    const int t = blockIdx.x;
    const int tid = threadIdx.x;
    const int K4 = K >> 2;

    for (int i = tid; i < K4; i += 512) {
        reinterpret_cast<float4*>(xrow)[i] =
            reinterpret_cast<const float4*>(xin + (size_t)t * K)[i];
    }
    __syncthreads();

    if (tid < G4) {
        const float4* wr = reinterpret_cast<const float4*>(W + (size_t)tid * K);
        float acc = bih[tid] + bhh[tid];
        #pragma unroll 5
        for (int k = 0; k < K4; ++k) {
            float4 w4 = wr[k];
            float4 x4 = reinterpret_cast<const float4*>(xrow)[k];
            acc = fmaf(w4.x, x4.x, acc);
            acc = fmaf(w4.y, x4.y, acc);
            acc = fmaf(w4.z, x4.z, acc);
            acc = fmaf(w4.w, x4.w, acc);
        }
        const int unit = tid % 100;
        const int gate = tid / 100;
        xpT[(size_t)t * G4 + unit * 4 + gate] = acc;
    }
}

// ---------------------------------------------------------------------------
// lstm_seq: 256 threads (4 waves, 1/SIMD). Thread (hf, j): hf = tid>>7
// (k-half: hf0 = k[0,52), hf1 = k[52,100)), j = tid&127 (unit, active j<100).
// Each thread computes all 4 gate partial dots for unit j over its k-half,
// with Whh slices in VGPRs and h broadcast via readlane->SGPR (no LDS reads
// in the inner loop). hf1 writes partials to LDS; hf0 combines, applies
// activations, owns (c,h), writes h to LDS + hseq. Two barriers per step.
// ---------------------------------------------------------------------------
__global__ __launch_bounds__(256, 1) void lstm_seq(
    const float* __restrict__ xpT,   // [SEQ][100][4] (i,f,g,o)
    const float* __restrict__ Whh,   // [400][100], rows gate*100+unit
    float* __restrict__ hseq)        // [SEQ][100]
{
    __shared__ __align__(16) float h_lds[128];     // h[0..99], rest zero pad
    __shared__ __align__(16) float4 part_lds[100]; // hf1 partial gate sums

    const int tid  = threadIdx.x;
    const int lane = tid & 63;
    const int hf   = tid >> 7;
    const int j    = tid & 127;
    const bool active = (j < 100);
    const int kb  = hf ? 52 : 0;     // k start (float4-aligned: 52*4=208 B)
    const int nc  = hf ? 12 : 13;    // real float4 chunks (48 / 52 floats)
    const int kb4 = hf ? 13 : 0;     // float4 index into h_lds

    // --- load Whh slices into registers: w[gate][2*chunk + {lo,hi}] ---
    v2 w[4][26];
    #pragma unroll
    for (int g = 0; g < 4; ++g)
        #pragma unroll
        for (int cc = 0; cc < 26; ++cc) w[g][cc] = v2{0.f, 0.f};
    if (active) {
        #pragma unroll
        for (int g = 0; g < 4; ++g) {
            const float* row = Whh + (size_t)(g * 100 + j) * 100 + kb;
            #pragma unroll
            for (int cc = 0; cc < 13; ++cc) {
                if (cc < nc) {
                    float4 t4 = reinterpret_cast<const float4*>(row)[cc];
                    w[g][2 * cc]     = v2{t4.x, t4.y};
                    w[g][2 * cc + 1] = v2{t4.z, t4.w};
                }
            }
        }
    }

    // --- init state ---
    if (tid < 128) h_lds[tid] = 0.f;
    float c = 0.f;
    float4 xp4 = make_float4(0.f, 0.f, 0.f, 0.f);
    if (hf == 0 && active)
        xp4 = *reinterpret_cast<const float4*>(xpT + (size_t)j * 4);
    __syncthreads();

    const float4* h4 = reinterpret_cast<const float4*>(h_lds);

    for (int t = 0; t < SEQ; ++t) {
        // distributed h load: lane l holds float4 chunk l of this wave's half
        float4 hv = h4[kb4 + (lane & 15)];

        v2 ai = {0.f, 0.f}, af = {0.f, 0.f}, ag = {0.f, 0.f}, ao = {0.f, 0.f};
        if (active) {
            #pragma unroll
            for (int cc = 0; cc < 13; ++cc) {
                v2 ha = {rdlane(hv.x, cc), rdlane(hv.y, cc)};
                v2 hb = {rdlane(hv.z, cc), rdlane(hv.w, cc)};
                ai = fma2(w[0][2 * cc], ha, ai);
                af = fma2(w[1][2 * cc], ha, af);
                ag = fma2(w[2][2 * cc], ha, ag);
                ao = fma2(w[3][2 * cc], ha, ao);
                ai = fma2(w[0][2 * cc + 1], hb, ai);
                af = fma2(w[1][2 * cc + 1], hb, af);
                ag = fma2(w[2][2 * cc + 1], hb, ag);
                ao = fma2(w[3][2 * cc + 1], hb, ao);
            }
        }
        float pi = ai[0] + ai[1];
        float pf = af[0] + af[1];
        float pg = ag[0] + ag[1];
        float po = ao[0] + ao[1];

        if (hf == 1 && active)
            part_lds[j] = make_float4(pi, pf, pg, po);
        __syncthreads();

        if (hf == 0 && active) {
            float4 q = part_lds[j];
            float gi = xp4.x + pi + q.x;
            float gf = xp4.y + pf + q.y;
            float gg = xp4.z + pg + q.z;
            float go = xp4.w + po + q.w;
            float si = fast_sigmoid(gi);
            float sf = fast_sigmoid(gf);
            float so = fast_sigmoid(go);
            float tg = fast_tanh(gg);
            c = sf * c + si * tg;
            float h = so * fast_tanh(c);
            h_lds[j] = h;
            hseq[(size_t)t * HID + j] = h;
            if (t + 1 < SEQ)
                xp4 = *reinterpret_cast<const float4*>(
                    xpT + (size_t)(t + 1) * G4 + j * 4);
        }
        __syncthreads();
    }
}

// ---------------------------------------------------------------------------
// fc_blend: out[c] = dot(hlast, fcW[c]) + fcb[c], optionally (.+blend)*0.5
// ---------------------------------------------------------------------------
__global__ __launch_bounds__(256) void fc_blend(
    const float* __restrict__ hlast,   // [HID]
    const float* __restrict__ fcW,     // [NCLS][HID]
    const float* __restrict__ fcb,     // [NCLS]
    const float* __restrict__ blend,   // [NCLS] or nullptr
    float* __restrict__ outp, int do_blend)
{
    __shared__ __align__(16) float h_lds[HID];
    const int tid = threadIdx.x;
    if (tid < 25) {
        reinterpret_cast<float4*>(h_lds)[tid] =
            reinterpret_cast<const float4*>(hlast)[tid];
    }
    __syncthreads();

    const int cidx = blockIdx.x * 256 + tid;
    const float4* wr = reinterpret_cast<const float4*>(fcW + (size_t)cidx * HID);
    float acc = fcb[cidx];
    #pragma unroll
    for (int k = 0; k < 25; ++k) {
        float4 w4 = wr[k];
        float4 h4 = reinterpret_cast<const float4*>(h_lds)[k];
        acc = fmaf(w4.x, h4.x, acc);
        acc = fmaf(w4.y, h4.y, acc);
        acc = fmaf(w4.z, h4.z, acc);
        acc = fmaf(w4.w, h4.w, acc);
    }
    if (do_blend) acc = (acc + blend[cidx]) * 0.5f;
    outp[cidx] = acc;
}

// ---------------------------------------------------------------------------
extern "C" void kernel_launch(void* const* d_in, const int* in_sizes, int n_in,
                              void* d_out, int out_size, void* d_ws, size_t ws_size,
                              hipStream_t stream)
{
    const float* x    = (const float*)d_in[0];
    const float* xn   = (const float*)d_in[1];
    const float* xnn  = (const float*)d_in[2];
    const float* Wih0 = (const float*)d_in[3];  // (3, 400, 640)
    const float* WihR = (const float*)d_in[4];  // (3, 3, 400, 100)
    const float* Whh  = (const float*)d_in[5];  // (3, 4, 400, 100)
    const float* bih  = (const float*)d_in[6];  // (3, 4, 400)
    const float* bhh  = (const float*)d_in[7];  // (3, 4, 400)
    const float* fcW  = (const float*)d_in[8];  // (3, 307200, 100)
    const float* fcb  = (const float*)d_in[9];  // (3, 307200)
    float* outp = (float*)d_out;
    float* ws = (float*)d_ws;

    float* xp  = ws;            // 192000 f32 (xpT: [SEQ][100][4])
    float* hA  = ws + 192000;   //  48000 f32
    float* hB  = ws + 240000;   //  48000 f32
    float* cur = ws + 288000;   // 307200 f32

    for (int s = 0; s < 3; ++s) {
        const float* stage_in = (s == 0) ? x : cur;

        proj_kernel<<<SEQ, 512, 0, stream>>>(
            stage_in, Wih0 + (size_t)s * G4 * INP,
            bih + (size_t)(s * 4 + 0) * G4, bhh + (size_t)(s * 4 + 0) * G4,
            xp, INP);
        lstm_seq<<<1, 256, 0, stream>>>(
            xp, Whh + (size_t)(s * 4 + 0) * G4 * HID, hA);

        float* hin = hA;
        float* hout = hB;
        for (int l = 1; l < 4; ++l) {
            proj_kernel<<<SEQ, 512, 0, stream>>>(
                hin, WihR + (size_t)(s * 3 + (l - 1)) * G4 * HID,
                bih + (size_t)(s * 4 + l) * G4, bhh + (size_t)(s * 4 + l) * G4,
                xp, HID);
            lstm_seq<<<1, 256, 0, stream>>>(
                xp, Whh + (size_t)(s * 4 + l) * G4 * HID, hout);
            float* tmp = hin; hin = hout; hout = tmp;
        }

        const float* blend = (s == 0) ? xn : (s == 1) ? xnn : nullptr;
        float* dst = (s == 2) ? outp : cur;
        fc_blend<<<NCLS / 256, 256, 0, stream>>>(
            hin + (size_t)(SEQ - 1) * HID,
            fcW + (size_t)s * NCLS * HID, fcb + (size_t)s * NCLS,
            blend, dst, (s < 2) ? 1 : 0);
    }
}

// Round 3
// 2009.479 us; speedup vs baseline: 2.6563x; 1.9912x over previous
//
#include <hip/hip_runtime.h>
#include <hip/hip_bf16.h>

#define HID   100
#define SEQ   480
#define INP   640
#define NCLS  307200
#define G4    400   // 4*HID
#define TILE  16
#define NTILE (SEQ / TILE)

typedef float v2 __attribute__((ext_vector_type(2)));

__device__ __forceinline__ v2 fma2(v2 a, v2 b, v2 c) {
    return __builtin_elementwise_fma(a, b, c);
}
__device__ __forceinline__ float fast_sigmoid(float x) {
    return __builtin_amdgcn_rcpf(1.f + __expf(-x));
}
__device__ __forceinline__ float fast_tanh(float x) {
    return 1.f - 2.f * __builtin_amdgcn_rcpf(__expf(2.f * x) + 1.f);
}

// ---------------------------------------------------------------------------
// proj: layer-0 input projection for a whole stage, one block per timestep.
// Writes TRANSPOSED unit-major: xp0T[t][unit][gate], bias included.
// ---------------------------------------------------------------------------
__global__ __launch_bounds__(512) void proj_kernel(
    const float* __restrict__ xin, const float* __restrict__ W,
    const float* __restrict__ bih, const float* __restrict__ bhh,
    float* __restrict__ xpT, int K)
{
    __shared__ __align__(16) float xrow[INP];
    const int t = blockIdx.x;
    const int tid = threadIdx.x;
    const int K4 = K >> 2;

    for (int i = tid; i < K4; i += 512) {
        reinterpret_cast<float4*>(xrow)[i] =
            reinterpret_cast<const float4*>(xin + (size_t)t * K)[i];
    }
    __syncthreads();

    if (tid < G4) {
        const float4* wr = reinterpret_cast<const float4*>(W + (size_t)tid * K);
        float acc = bih[tid] + bhh[tid];
        #pragma unroll 5
        for (int k = 0; k < K4; ++k) {
            float4 w4 = wr[k];
            float4 x4 = reinterpret_cast<const float4*>(xrow)[k];
            acc = fmaf(w4.x, x4.x, acc);
            acc = fmaf(w4.y, x4.y, acc);
            acc = fmaf(w4.z, x4.z, acc);
            acc = fmaf(w4.w, x4.w, acc);
        }
        const int unit = tid % 100;
        const int gate = tid / 100;
        xpT[(size_t)t * G4 + unit * 4 + gate] = acc;
    }
}

// ---------------------------------------------------------------------------
// lstm_stage: 4 blocks = 4 layers, pipelined with tile-granular (16-step)
// producer->consumer handoff through global hseq + agent-scope flags.
//
// Block layout (512 thr, 8 waves): way = wid>>1 in [0,4):
//   mat = way>>1 (0: recurrent Whh, 1: input Wih; layer 0 has no mat1 work),
//   kh  = way&1  (k in [0,52) / [52,100), zero-padded to 52),
//   j   = tid&127 (unit, active j<100).
// Thread holds 4 gates x 52 k weights as v2 (208 VGPRs). h broadcast via
// uniform-address ds_read_b128 -> v_pk_fma_f32. Way 1..3 write partial gate
// sums to LDS; way 0 combines + activations + owns (c,h).
// All global traffic is per-tile bulk copies (off the per-step barrier path).
// ---------------------------------------------------------------------------
__global__ __launch_bounds__(512, 2) void lstm_stage(
    const float* __restrict__ xp0T,   // [SEQ][400] layer-0 xp (bias included)
    const float* __restrict__ WihS,   // [3][400][100] layers 1..3 input W
    const float* __restrict__ WhhS,   // [4][400][100]
    const float* __restrict__ bihS,   // [4][400]
    const float* __restrict__ bhhS,   // [4][400]
    float* __restrict__ hseq,         // [4][SEQ][100] workspace
    int* __restrict__ flags)          // [4], zeroed before launch
{
    __shared__ __align__(16) float h_lds[128];            // own h, pad zeros
    __shared__ __align__(16) float hprev_lds[TILE * 128]; // consumer tile
    __shared__ __align__(16) float xp_lds[TILE * G4];     // layer-0 xp tile
    __shared__ __align__(16) float parts[3][128][4];      // partial gate sums
    __shared__ __align__(16) float hist[TILE * 128];      // own h history

    const int l   = blockIdx.x;
    const int tid = threadIdx.x;
    const int wid = tid >> 6;
    const int way = wid >> 1;
    const int mat = way >> 1;
    const int kh  = way & 1;
    const int j   = tid & 127;
    const bool active  = (j < 100);
    const bool compute = active && (mat == 0 || l > 0);
    const int k0 = kh * 52;

    // ---- load weight slices into registers (zero-padded) ----
    v2 w2[4][26];
    #pragma unroll
    for (int g = 0; g < 4; ++g)
        #pragma unroll
        for (int cc = 0; cc < 26; ++cc) w2[g][cc] = v2{0.f, 0.f};
    if (compute) {
        const float* Wm = mat ? (WihS + (size_t)(l - 1) * G4 * HID)
                              : (WhhS + (size_t)l * G4 * HID);
        const int nf4 = kh ? 12 : 13;  // 48 or 52 real floats
        #pragma unroll
        for (int g = 0; g < 4; ++g) {
            const float* row = Wm + (size_t)(g * 100 + j) * HID + k0;
            #pragma unroll
            for (int cc = 0; cc < 13; ++cc) {
                if (cc < nf4) {
                    float4 t4 = *reinterpret_cast<const float4*>(row + 4 * cc);
                    w2[g][2 * cc]     = v2{t4.x, t4.y};
                    w2[g][2 * cc + 1] = v2{t4.z, t4.w};
                }
            }
        }
    }
    float b0 = 0.f, b1 = 0.f, b2 = 0.f, b3 = 0.f;
    if (way == 0 && active && l > 0) {
        b0 = bihS[l * G4 + 0 * 100 + j] + bhhS[l * G4 + 0 * 100 + j];
        b1 = bihS[l * G4 + 1 * 100 + j] + bhhS[l * G4 + 1 * 100 + j];
        b2 = bihS[l * G4 + 2 * 100 + j] + bhhS[l * G4 + 2 * 100 + j];
        b3 = bihS[l * G4 + 3 * 100 + j] + bhhS[l * G4 + 3 * 100 + j];
    }
    if (tid < 128) h_lds[tid] = 0.f;
    float c = 0.f;
    const float* hseq_prev = hseq + (size_t)(l - 1) * SEQ * HID;
    float* hseq_own        = hseq + (size_t)l * SEQ * HID;
    __syncthreads();

    for (int tile = 0; tile < NTILE; ++tile) {
        const int t0 = tile * TILE;

        // ---- tile prologue: fetch this tile's input ----
        if (l == 0) {
            const float4* src =
                reinterpret_cast<const float4*>(xp0T + (size_t)t0 * G4);
            float4* dst = reinterpret_cast<float4*>(xp_lds);
            for (int i = tid; i < TILE * G4 / 4; i += 512) dst[i] = src[i];
        } else {
            const int want = t0 + TILE;
            while (__hip_atomic_load(&flags[l - 1], __ATOMIC_ACQUIRE,
                                     __HIP_MEMORY_SCOPE_AGENT) < want) {}
            for (int i = tid; i < TILE * 128; i += 512) {
                const int tt = i >> 7, jj = i & 127;
                hprev_lds[i] = (jj < 100)
                    ? __hip_atomic_load(
                          &hseq_prev[(size_t)(t0 + tt) * HID + jj],
                          __ATOMIC_RELAXED, __HIP_MEMORY_SCOPE_AGENT)
                    : 0.f;
            }
        }
        __syncthreads();

        // ---- 16 recurrent steps ----
        for (int tt = 0; tt < TILE; ++tt) {
            v2 a0 = {0.f, 0.f}, a1 = {0.f, 0.f};
            v2 a2 = {0.f, 0.f}, a3 = {0.f, 0.f};
            const float* hb = mat ? (hprev_lds + tt * 128 + k0) : (h_lds + k0);
            if (compute) {
                #pragma unroll
                for (int cc = 0; cc < 13; ++cc) {
                    float4 hv = *reinterpret_cast<const float4*>(hb + 4 * cc);
                    v2 hlo = v2{hv.x, hv.y};
                    v2 hhi = v2{hv.z, hv.w};
                    a0 = fma2(w2[0][2 * cc], hlo, a0);
                    a1 = fma2(w2[1][2 * cc], hlo, a1);
                    a2 = fma2(w2[2][2 * cc], hlo, a2);
                    a3 = fma2(w2[3][2 * cc], hlo, a3);
                    a0 = fma2(w2[0][2 * cc + 1], hhi, a0);
                    a1 = fma2(w2[1][2 * cc + 1], hhi, a1);
                    a2 = fma2(w2[2][2 * cc + 1], hhi, a2);
                    a3 = fma2(w2[3][2 * cc + 1], hhi, a3);
                }
                if (way > 0) {
                    *reinterpret_cast<float4*>(&parts[way - 1][j][0]) =
                        make_float4(a0[0] + a0[1], a1[0] + a1[1],
                                    a2[0] + a2[1], a3[0] + a3[1]);
                }
            }
            __syncthreads();

            if (way == 0 && active) {
                float gi = a0[0] + a0[1];
                float gf = a1[0] + a1[1];
                float gg = a2[0] + a2[1];
                float go = a3[0] + a3[1];
                float4 q0 = *reinterpret_cast<const float4*>(&parts[0][j][0]);
                gi += q0.x; gf += q0.y; gg += q0.z; go += q0.w;
                if (l == 0) {
                    float4 xq = *reinterpret_cast<const float4*>(
                        &xp_lds[tt * G4 + (j << 2)]);
                    gi += xq.x; gf += xq.y; gg += xq.z; go += xq.w;
                } else {
                    float4 q1 = *reinterpret_cast<const float4*>(&parts[1][j][0]);
                    float4 q2 = *reinterpret_cast<const float4*>(&parts[2][j][0]);
                    gi += q1.x + q2.x + b0;
                    gf += q1.y + q2.y + b1;
                    gg += q1.z + q2.z + b2;
                    go += q1.w + q2.w + b3;
                }
                float si = fast_sigmoid(gi);
                float sf = fast_sigmoid(gf);
                float so = fast_sigmoid(go);
                float tg = fast_tanh(gg);
                c = sf * c + si * tg;
                float h = so * fast_tanh(c);
                h_lds[j] = h;
                hist[tt * 128 + j] = h;
            }
            __syncthreads();
        }

        // ---- tile epilogue: flush h history, publish flag ----
        for (int i = tid; i < TILE * 128; i += 512) {
            const int tt = i >> 7, jj = i & 127;
            if (jj < 100)
                hseq_own[(size_t)(t0 + tt) * HID + jj] = hist[i];
        }
        __syncthreads();  // drains vmem (compiler emits vmcnt(0) before barrier)
        if (tid == 0 && l < 3)
            __hip_atomic_store(&flags[l], t0 + TILE, __ATOMIC_RELEASE,
                               __HIP_MEMORY_SCOPE_AGENT);
    }
}

// ---------------------------------------------------------------------------
// fc_blend: out[c] = dot(hlast, fcW[c]) + fcb[c], optionally (.+blend)*0.5
// ---------------------------------------------------------------------------
__global__ __launch_bounds__(256) void fc_blend(
    const float* __restrict__ hlast,   // [HID]
    const float* __restrict__ fcW,     // [NCLS][HID]
    const float* __restrict__ fcb,     // [NCLS]
    const float* __restrict__ blend,   // [NCLS] or nullptr
    float* __restrict__ outp, int do_blend)
{
    __shared__ __align__(16) float h_lds[HID];
    const int tid = threadIdx.x;
    if (tid < 25) {
        reinterpret_cast<float4*>(h_lds)[tid] =
            reinterpret_cast<const float4*>(hlast)[tid];
    }
    __syncthreads();

    const int cidx = blockIdx.x * 256 + tid;
    const float4* wr = reinterpret_cast<const float4*>(fcW + (size_t)cidx * HID);
    float acc = fcb[cidx];
    #pragma unroll
    for (int k = 0; k < 25; ++k) {
        float4 w4 = wr[k];
        float4 h4 = reinterpret_cast<const float4*>(h_lds)[k];
        acc = fmaf(w4.x, h4.x, acc);
        acc = fmaf(w4.y, h4.y, acc);
        acc = fmaf(w4.z, h4.z, acc);
        acc = fmaf(w4.w, h4.w, acc);
    }
    if (do_blend) acc = (acc + blend[cidx]) * 0.5f;
    outp[cidx] = acc;
}

// ---------------------------------------------------------------------------
extern "C" void kernel_launch(void* const* d_in, const int* in_sizes, int n_in,
                              void* d_out, int out_size, void* d_ws, size_t ws_size,
                              hipStream_t stream)
{
    const float* x    = (const float*)d_in[0];
    const float* xn   = (const float*)d_in[1];
    const float* xnn  = (const float*)d_in[2];
    const float* Wih0 = (const float*)d_in[3];  // (3, 400, 640)
    const float* WihR = (const float*)d_in[4];  // (3, 3, 400, 100)
    const float* Whh  = (const float*)d_in[5];  // (3, 4, 400, 100)
    const float* bih  = (const float*)d_in[6];  // (3, 4, 400)
    const float* bhh  = (const float*)d_in[7];  // (3, 4, 400)
    const float* fcW  = (const float*)d_in[8];  // (3, 307200, 100)
    const float* fcb  = (const float*)d_in[9];  // (3, 307200)
    float* outp = (float*)d_out;
    float* ws = (float*)d_ws;

    float* xp0T  = ws;                 // 192000 f32
    float* hseq  = ws + 192000;        // 4*480*100 = 192000 f32
    float* cur   = ws + 384000;        // 307200 f32
    int*   flags = (int*)(ws + 691200);  // 12 ints

    hipMemsetAsync(flags, 0, 12 * sizeof(int), stream);

    for (int s = 0; s < 3; ++s) {
        const float* stage_in = (s == 0) ? x : cur;

        proj_kernel<<<SEQ, 512, 0, stream>>>(
            stage_in, Wih0 + (size_t)s * G4 * INP,
            bih + (size_t)(s * 4 + 0) * G4, bhh + (size_t)(s * 4 + 0) * G4,
            xp0T, INP);

        lstm_stage<<<4, 512, 0, stream>>>(
            xp0T,
            WihR + (size_t)s * 3 * G4 * HID,
            Whh  + (size_t)s * 4 * G4 * HID,
            bih  + (size_t)s * 4 * G4,
            bhh  + (size_t)s * 4 * G4,
            hseq, flags + s * 4);

        const float* blend = (s == 0) ? xn : (s == 1) ? xnn : nullptr;
        float* dst = (s == 2) ? outp : cur;
        fc_blend<<<NCLS / 256, 256, 0, stream>>>(
            hseq + (size_t)3 * SEQ * HID + (size_t)(SEQ - 1) * HID,
            fcW + (size_t)s * NCLS * HID, fcb + (size_t)s * NCLS,
            blend, dst, (s < 2) ? 1 : 0);
    }
}

// Round 4
// 1915.712 us; speedup vs baseline: 2.7863x; 1.0489x over previous
//
#include <hip/hip_runtime.h>
#include <hip/hip_bf16.h>

#define HID   100
#define SEQ   480
#define INP   640
#define NCLS  307200
#define G4    400
#define TILE  16
#define NTILE 30
#define RING  4

typedef float    v2    __attribute__((ext_vector_type(2)));
typedef _Float16 f16x8 __attribute__((ext_vector_type(8)));
typedef float    f32x4 __attribute__((ext_vector_type(4)));

__device__ __forceinline__ v2 fma2(v2 a, v2 b, v2 c) {
    return __builtin_elementwise_fma(a, b, c);
}
__device__ __forceinline__ float fast_sigmoid(float x) {
    return __builtin_amdgcn_rcpf(1.f + __expf(-x));
}
__device__ __forceinline__ float fast_tanh(float x) {
    return 1.f - 2.f * __builtin_amdgcn_rcpf(__expf(2.f * x) + 1.f);
}
__device__ __forceinline__ int ld_acq(const int* p) {
    return __hip_atomic_load(p, __ATOMIC_ACQUIRE, __HIP_MEMORY_SCOPE_AGENT);
}
__device__ __forceinline__ void st_rel(int* p, int v) {
    __hip_atomic_store(p, v, __ATOMIC_RELEASE, __HIP_MEMORY_SCOPE_AGENT);
}
__device__ __forceinline__ f16x8 zero8() {
    f16x8 v;
    #pragma unroll
    for (int i = 0; i < 8; ++i) v[i] = (_Float16)0.f;
    return v;
}
__device__ __forceinline__ f16x8 cvt8(float4 a, float4 b) {
    f16x8 v;
    v[0] = (_Float16)a.x; v[1] = (_Float16)a.y;
    v[2] = (_Float16)a.z; v[3] = (_Float16)a.w;
    v[4] = (_Float16)b.x; v[5] = (_Float16)b.y;
    v[6] = (_Float16)b.z; v[7] = (_Float16)b.w;
    return v;
}
__device__ __forceinline__ f16x8 cvt4z(float4 a) {
    f16x8 v = zero8();
    v[0] = (_Float16)a.x; v[1] = (_Float16)a.y;
    v[2] = (_Float16)a.z; v[3] = (_Float16)a.w;
    return v;
}

// ---------------------------------------------------------------------------
// stage_kernel: 124 blocks.
//   blocks 0..3   : lstm layer l (serial recurrence, Whh only)
//   blocks 4..123 : proj workers, p = bid-4 -> (l = p/30, t = p%30)
// Workers compute xp tile [16][400] = input_tile x Wih^T + bias via MFMA f16
// into a 4-slot ring per layer; lstm blocks consume via flags.
//   hflag[l]  : timesteps published by lstm l into hseq16
//   rdflag[l] : tiles consumed (copied to LDS) by lstm l  -> ring reuse gate
//   xpflag[l*30+t] : xp tile ready
// ---------------------------------------------------------------------------
__global__ __launch_bounds__(256, 1) void stage_kernel(
    const float* __restrict__ xin,    // [480][640] stage input
    const float* __restrict__ Wih0,   // [400][640]
    const float* __restrict__ WihR,   // [3][400][100]
    const float* __restrict__ Whh,    // [4][400][100]
    const float* __restrict__ bih,    // [4][400]
    const float* __restrict__ bhh,    // [4][400]
    float* __restrict__ ring,         // [4][RING][16][400]
    _Float16* __restrict__ hseq16,    // [4][480][104] (cols 100..103 zero)
    int* __restrict__ flags)          // [128]
{
    const int bid = blockIdx.x;
    const int tid = threadIdx.x;
    int* hflag  = flags;
    int* rdflag = flags + 4;
    int* xpflag = flags + 8;

    if (bid >= 4) {
        // ================= proj worker =================
        const int p  = bid - 4;
        const int l  = p / NTILE;
        const int t  = p % NTILE;
        const int t0 = t * TILE;
        const int lane = tid & 63;
        const int wid  = tid >> 6;
        const int col  = lane & 15;   // A row (tt) and B col (n) within tile
        const int kb   = lane >> 4;   // k-subchunk

        if (l > 0) { while (ld_acq(&hflag[l - 1]) < t0 + TILE) {} }
        if (t >= RING) { while (ld_acq(&rdflag[l]) < t - (RING - 1)) {} }

        float* slot = ring + ((size_t)l * RING + (t & (RING - 1))) * (TILE * G4);

        if (l == 0) {
            // A = xin f32 -> f16, K = 640 = 20 ksteps
            f16x8 af[20];
            const float* arow = xin + (size_t)(t0 + col) * INP;
            #pragma unroll
            for (int ks = 0; ks < 20; ++ks) {
                const float* ap = arow + ks * 32 + kb * 8;
                af[ks] = cvt8(*(const float4*)ap, *(const float4*)(ap + 4));
            }
            for (int tile = wid; tile < 25; tile += 4) {
                const int n = tile * 16 + col;
                const float* brow = Wih0 + (size_t)n * INP;
                const float bn = bih[n] + bhh[n];
                f32x4 acc = {bn, bn, bn, bn};
                #pragma unroll
                for (int ks = 0; ks < 20; ++ks) {
                    const float* bp = brow + ks * 32 + kb * 8;
                    f16x8 bf = cvt8(*(const float4*)bp, *(const float4*)(bp + 4));
                    acc = __builtin_amdgcn_mfma_f32_16x16x32_f16(af[ks], bf, acc, 0, 0, 0);
                }
                const int u = n % 100, g = n / 100;
                #pragma unroll
                for (int r = 0; r < 4; ++r)
                    slot[(size_t)(kb * 4 + r) * G4 + u * 4 + g] = acc[r];
            }
        } else {
            // A = hseq16[l-1] f16, K = 100 -> 3 full ksteps + masked tail
            f16x8 af[4];
            const _Float16* arow = hseq16 + ((size_t)(l - 1) * SEQ + t0 + col) * 104;
            af[0] = *(const f16x8*)(arow + kb * 8);
            af[1] = *(const f16x8*)(arow + 32 + kb * 8);
            af[2] = *(const f16x8*)(arow + 64 + kb * 8);
            af[3] = (kb == 0) ? *(const f16x8*)(arow + 96) : zero8();
            for (int tile = wid; tile < 25; tile += 4) {
                const int n = tile * 16 + col;
                const float* brow = WihR + ((size_t)(l - 1) * G4 + n) * HID;
                const float bn = bih[l * G4 + n] + bhh[l * G4 + n];
                f32x4 acc = {bn, bn, bn, bn};
                #pragma unroll
                for (int ks = 0; ks < 3; ++ks) {
                    const float* bp = brow + ks * 32 + kb * 8;
                    f16x8 bf = cvt8(*(const float4*)bp, *(const float4*)(bp + 4));
                    acc = __builtin_amdgcn_mfma_f32_16x16x32_f16(af[ks], bf, acc, 0, 0, 0);
                }
                f16x8 bf3 = (kb == 0) ? cvt4z(*(const float4*)(brow + 96)) : zero8();
                acc = __builtin_amdgcn_mfma_f32_16x16x32_f16(af[3], bf3, acc, 0, 0, 0);
                const int u = n % 100, g = n / 100;
                #pragma unroll
                for (int r = 0; r < 4; ++r)
                    slot[(size_t)(kb * 4 + r) * G4 + u * 4 + g] = acc[r];
            }
        }
        __syncthreads();   // drain stores
        if (tid == 0) st_rel(&xpflag[p], 1);
        return;
    }

    // ================= lstm layer block =================
    __shared__ __align__(16) float xp_lds[TILE * G4];   // 25.6 KB
    __shared__ __align__(16) float h_lds[128];
    __shared__ __align__(16) float4 parts[128];
    __shared__ __align__(16) _Float16 hist16[TILE * 104];

    const int l  = bid;
    const int kh = tid >> 7;        // k-half: 0 -> [0,52), 1 -> [52,104)
    const int j  = tid & 127;       // unit
    const int k0 = kh * 52;
    const bool own = (kh == 0) && (j < 100);

    // weights: 4 gates x 52 k in f32 v2 regs (zero-padded)
    v2 w2[4][26];
    #pragma unroll
    for (int g = 0; g < 4; ++g)
        #pragma unroll
        for (int cc = 0; cc < 26; ++cc) w2[g][cc] = v2{0.f, 0.f};
    if (j < 100) {
        const int nf4 = kh ? 12 : 13;
        #pragma unroll
        for (int g = 0; g < 4; ++g) {
            const float* row = Whh + ((size_t)(l * G4 + g * 100 + j)) * HID + k0;
            #pragma unroll
            for (int cc = 0; cc < 13; ++cc) {
                if (cc < nf4) {
                    float4 t4 = *(const float4*)(row + 4 * cc);
                    w2[g][2 * cc]     = v2{t4.x, t4.y};
                    w2[g][2 * cc + 1] = v2{t4.z, t4.w};
                }
            }
        }
    }
    if (tid < 128) h_lds[tid] = 0.f;
    for (int i = tid; i < TILE * 104; i += 256) hist16[i] = (_Float16)0.f;
    float c = 0.f;
    __syncthreads();

    for (int t = 0; t < NTILE; ++t) {
        // fetch xp tile from ring
        while (ld_acq(&xpflag[l * NTILE + t]) < 1) {}
        {
            const float4* src = (const float4*)(ring +
                ((size_t)l * RING + (t & (RING - 1))) * (TILE * G4));
            float4* dst = (float4*)xp_lds;
            for (int i = tid; i < TILE * G4 / 4; i += 256) dst[i] = src[i];
        }
        __syncthreads();
        if (tid == 0) st_rel(&rdflag[l], t + 1);

        for (int tt = 0; tt < TILE; ++tt) {
            float4 hs[13];
            const float4* hp = (const float4*)(h_lds + k0);
            #pragma unroll
            for (int cc = 0; cc < 13; ++cc) hs[cc] = hp[cc];

            v2 a0 = {0.f, 0.f}, a1 = {0.f, 0.f};
            v2 a2 = {0.f, 0.f}, a3 = {0.f, 0.f};
            #pragma unroll
            for (int cc = 0; cc < 13; ++cc) {
                v2 lo = v2{hs[cc].x, hs[cc].y};
                v2 hi = v2{hs[cc].z, hs[cc].w};
                a0 = fma2(w2[0][2 * cc], lo, a0);
                a1 = fma2(w2[1][2 * cc], lo, a1);
                a2 = fma2(w2[2][2 * cc], lo, a2);
                a3 = fma2(w2[3][2 * cc], lo, a3);
                a0 = fma2(w2[0][2 * cc + 1], hi, a0);
                a1 = fma2(w2[1][2 * cc + 1], hi, a1);
                a2 = fma2(w2[2][2 * cc + 1], hi, a2);
                a3 = fma2(w2[3][2 * cc + 1], hi, a3);
            }
            if (kh == 1 && j < 100)
                parts[j] = make_float4(a0[0] + a0[1], a1[0] + a1[1],
                                       a2[0] + a2[1], a3[0] + a3[1]);
            __syncthreads();

            if (own) {
                float4 q  = parts[j];
                float4 xq = *(const float4*)(xp_lds + tt * G4 + (j << 2));
                float gi = a0[0] + a0[1] + q.x + xq.x;
                float gf = a1[0] + a1[1] + q.y + xq.y;
                float gg = a2[0] + a2[1] + q.z + xq.z;
                float go = a3[0] + a3[1] + q.w + xq.w;
                float si = fast_sigmoid(gi);
                float sf = fast_sigmoid(gf);
                float so = fast_sigmoid(go);
                float tg = fast_tanh(gg);
                c = sf * c + si * tg;
                float h = so * fast_tanh(c);
                h_lds[j] = h;
                hist16[tt * 104 + j] = (_Float16)h;
            }
            __syncthreads();
        }

        // flush h history tile (f16, padded rows) and publish
        {
            const uint* hsrc = (const uint*)hist16;
            uint* hdst = (uint*)(hseq16 + ((size_t)l * SEQ + t * TILE) * 104);
            for (int i = tid; i < TILE * 52; i += 256) hdst[i] = hsrc[i];
        }
        __syncthreads();
        if (tid == 0) st_rel(&hflag[l], (t + 1) * TILE);
    }
}

// ---------------------------------------------------------------------------
// fc_blend: out[c] = dot(h_last, fcW[c]) + fcb[c]; optional (.+blend)*0.5
// ---------------------------------------------------------------------------
__global__ __launch_bounds__(256) void fc_blend(
    const _Float16* __restrict__ hlast,  // [104] padded row
    const float* __restrict__ fcW,       // [NCLS][HID]
    const float* __restrict__ fcb,       // [NCLS]
    const float* __restrict__ blend,     // [NCLS] or nullptr
    float* __restrict__ outp, int do_blend)
{
    __shared__ __align__(16) float h_lds[HID + 4];
    const int tid = threadIdx.x;
    if (tid < 104) h_lds[tid] = (tid < 100) ? (float)hlast[tid] : 0.f;
    __syncthreads();

    const int cidx = blockIdx.x * 256 + tid;
    const float4* wr = reinterpret_cast<const float4*>(fcW + (size_t)cidx * HID);
    float acc = fcb[cidx];
    #pragma unroll
    for (int k = 0; k < 25; ++k) {
        float4 w4 = wr[k];
        float4 h4 = reinterpret_cast<const float4*>(h_lds)[k];
        acc = fmaf(w4.x, h4.x, acc);
        acc = fmaf(w4.y, h4.y, acc);
        acc = fmaf(w4.z, h4.z, acc);
        acc = fmaf(w4.w, h4.w, acc);
    }
    if (do_blend) acc = (acc + blend[cidx]) * 0.5f;
    outp[cidx] = acc;
}

// ---------------------------------------------------------------------------
extern "C" void kernel_launch(void* const* d_in, const int* in_sizes, int n_in,
                              void* d_out, int out_size, void* d_ws, size_t ws_size,
                              hipStream_t stream)
{
    const float* x    = (const float*)d_in[0];
    const float* xn   = (const float*)d_in[1];
    const float* xnn  = (const float*)d_in[2];
    const float* Wih0 = (const float*)d_in[3];  // (3, 400, 640)
    const float* WihR = (const float*)d_in[4];  // (3, 3, 400, 100)
    const float* Whh  = (const float*)d_in[5];  // (3, 4, 400, 100)
    const float* bih  = (const float*)d_in[6];  // (3, 4, 400)
    const float* bhh  = (const float*)d_in[7];  // (3, 4, 400)
    const float* fcW  = (const float*)d_in[8];  // (3, 307200, 100)
    const float* fcb  = (const float*)d_in[9];  // (3, 307200)
    float* outp = (float*)d_out;
    float* ws = (float*)d_ws;

    float*     ring   = ws;                                  // 102400 f32
    _Float16*  hseq16 = (_Float16*)(ws + 102400);            // 199680 f16 (=99840 f32)
    float*     cur    = ws + 102400 + 99840;                 // 307200 f32
    int*       flags  = (int*)(ws + 102400 + 99840 + 307200);// 3*128 ints

    hipMemsetAsync(flags, 0, 3 * 128 * sizeof(int), stream);

    for (int s = 0; s < 3; ++s) {
        const float* stage_in = (s == 0) ? x : cur;

        stage_kernel<<<4 + 4 * NTILE, 256, 0, stream>>>(
            stage_in,
            Wih0 + (size_t)s * G4 * INP,
            WihR + (size_t)s * 3 * G4 * HID,
            Whh  + (size_t)s * 4 * G4 * HID,
            bih  + (size_t)s * 4 * G4,
            bhh  + (size_t)s * 4 * G4,
            ring, hseq16, flags + s * 128);

        const float* blend = (s == 0) ? xn : (s == 1) ? xnn : nullptr;
        float* dst = (s == 2) ? outp : cur;
        fc_blend<<<NCLS / 256, 256, 0, stream>>>(
            hseq16 + ((size_t)3 * SEQ + SEQ - 1) * 104,
            fcW + (size_t)s * NCLS * HID, fcb + (size_t)s * NCLS,
            blend, dst, (s < 2) ? 1 : 0);
    }
}